// Round 3
// baseline (255.929 us; speedup 1.0000x reference)
//
#include <hip/hip_runtime.h>
#include <stdint.h>
#include <stddef.h>

// Problem constants (B, F, D) = (1024, 16, 64); P = 120
constexpr int NB = 1024;
constexpr int NF = 16;
constexpr int ND = 64;
constexpr int NP = 120;
constexpr int KD = ND * ND;          // 4096 contraction length per pair
constexpr int OUT_STRIDE = NP * ND;  // 7680 floats per batch row

constexpr int BM = 128;              // batch rows per block (was 256) -> 960 blocks, 4 blocks/CU

using floatx4 = __attribute__((ext_vector_type(4))) float;
using half8   = __attribute__((ext_vector_type(8))) _Float16;
using half2v  = __attribute__((ext_vector_type(2))) _Float16;
using fp16x2  = __attribute__((ext_vector_type(2))) __fp16;   // cvt_pkrtz return type
using uint4v  = __attribute__((ext_vector_type(4))) uint32_t;

constexpr int XT_STRIDE = BM;              // u16 per xi^T row (m-contiguous)
constexpr int BT_STRIDE = 72;              // u16 per W-tile row (144 B, 16B-aligned)
constexpr int BT_BUF    = ND * BT_STRIDE;  // elems per W buffer

// pack 2 f32 -> 2 fp16 (v_cvt_pkrtz_f16_f32, 1 VALU op)
__device__ __forceinline__ half2v pkh2(float f0, float f1) {
    fp16x2 h = __builtin_amdgcn_cvt_pkrtz(f0, f1);
    return __builtin_bit_cast(half2v, h);
}
__device__ __forceinline__ uint32_t pk16(float f0, float f1) {
    fp16x2 h = __builtin_amdgcn_cvt_pkrtz(f0, f1);
    return __builtin_bit_cast(uint32_t, h);
}
__device__ __forceinline__ uint16_t f16bits(float f) {
    return __builtin_bit_cast(uint16_t, (_Float16)f);   // RNE scalar cvt
}

__global__ __launch_bounds__(256, 4)
void outer_kernel(const float* __restrict__ x, const float* __restrict__ W,
                  const float* __restrict__ bias, float* __restrict__ out)
{
    __shared__ uint16_t lds_xit[ND * XT_STRIDE];  // xi^T fp16: 16,384 B
    __shared__ uint16_t lds_bt[2 * BT_BUF];       // W a-tile dbuf: 18,432 B (total 34,816 -> 4 blocks/CU)

    const int p  = blockIdx.x;        // pair 0..119
    const int b0 = blockIdx.y * BM;   // batch tile origin

    // triu_indices(16, k=1) order
    int icol = 0, rem = p;
    while (rem >= NF - 1 - icol) { rem -= NF - 1 - icol; ++icol; }
    const int jcol = icol + 1 + rem;

    const int t    = threadIdx.x;
    const int wave = t >> 6;
    const int lane = t & 63;
    const int r    = lane & 15;
    const int quad = lane >> 4;

    // ---- stage xi transposed: lds_xit[a*XT_STRIDE + m] = fp16(x[b0+m][icol][a]) ----
    // 256 threads cover 128 rows x 64 a: thread handles (row t>>1, a-half (t&1)*32)
    {
        const int mrow  = t >> 1;
        const int chalf = (t & 1) * 32;
        const float* src = x + (size_t)(b0 + mrow) * (NF * ND) + icol * ND + chalf;
        #pragma unroll
        for (int c = 0; c < 32; c += 4) {
            floatx4 v = *(const floatx4*)(src + c);
            lds_xit[(chalf + c + 0) * XT_STRIDE + mrow] = f16bits(v.x);
            lds_xit[(chalf + c + 1) * XT_STRIDE + mrow] = f16bits(v.y);
            lds_xit[(chalf + c + 2) * XT_STRIDE + mrow] = f16bits(v.z);
            lds_xit[(chalf + c + 3) * XT_STRIDE + mrow] = f16bits(v.w);
        }
    }

    // ---- loop-invariant xj as fp16 pairs, laid out to match the MFMA A-fragment ----
    // lane owns A[m = lane&15][k = quad*8 + j]; xjh[ms][ks*4+q] = (c, c+1) at c = ks*32 + quad*8 + 2q
    half2v xjh[2][8];
    #pragma unroll
    for (int ms = 0; ms < 2; ++ms) {
        const float* srow = x + (size_t)(b0 + wave*32 + ms*16 + r) * (NF * ND)
                              + jcol * ND + quad * 8;
        #pragma unroll
        for (int ks = 0; ks < 2; ++ks) {
            floatx4 v0 = *(const floatx4*)(srow + ks * 32);
            floatx4 v1 = *(const floatx4*)(srow + ks * 32 + 4);
            xjh[ms][ks*4 + 0] = pkh2(v0.x, v0.y);
            xjh[ms][ks*4 + 1] = pkh2(v0.z, v0.w);
            xjh[ms][ks*4 + 2] = pkh2(v1.x, v1.y);
            xjh[ms][ks*4 + 3] = pkh2(v1.z, v1.w);
        }
    }

    // ---- W staging: thread covers (n_st, c_st..c_st+15) of the 64x64 a-tile ----
    const int n_st = t >> 2;
    const int c_st = (t & 3) * 16;
    const float* wsrc = W + ((size_t)p * ND + n_st) * KD + c_st;
    uint16_t* bdst0 = &lds_bt[n_st * BT_STRIDE + c_st];

    floatx4 wreg[4];

    // prologue: stage W(0) into buf0; prefetch W(1) into wreg
    #pragma unroll
    for (int q = 0; q < 4; ++q) wreg[q] = *(const floatx4*)(wsrc + q * 4);
    {
        uint4v q0 = (uint4v){ pk16(wreg[0].x, wreg[0].y), pk16(wreg[0].z, wreg[0].w),
                              pk16(wreg[1].x, wreg[1].y), pk16(wreg[1].z, wreg[1].w) };
        uint4v q1 = (uint4v){ pk16(wreg[2].x, wreg[2].y), pk16(wreg[2].z, wreg[2].w),
                              pk16(wreg[3].x, wreg[3].y), pk16(wreg[3].z, wreg[3].w) };
        *(uint4v*)(bdst0)     = q0;
        *(uint4v*)(bdst0 + 8) = q1;
    }
    #pragma unroll
    for (int q = 0; q < 4; ++q) wreg[q] = *(const floatx4*)(wsrc + ND + q * 4);
    __syncthreads();

    floatx4 acc[2][4] = {};   // fp32 MFMA C-accumulators: all accumulation on the matrix pipe

    #pragma unroll 1
    for (int a = 0; a < ND; ++a) {
        const int cur = a & 1;
        const uint16_t* rbuf = lds_bt + cur * BT_BUF;  // holds W(a)

        // xi scalars for this a (broadcast across quads; conflict-free)
        uint32_t xiu[2];
        #pragma unroll
        for (int ms = 0; ms < 2; ++ms)
            xiu[ms] = lds_xit[a * XT_STRIDE + wave*32 + ms*16 + r];

        // B-fragments for all ns (issue LDS reads early; latency covered by A'-build)
        half8 bfr[4][2];
        #pragma unroll
        for (int ns = 0; ns < 4; ++ns) {
            const int brow = (ns*16 + r) * BT_STRIDE + quad * 8;
            bfr[ns][0] = *(const half8*)&rbuf[brow];
            bfr[ns][1] = *(const half8*)&rbuf[brow + 32];
        }

        // A' = (xi[m,a] * xj[m,c]) fragments — pure producer, no MFMA-result reads
        half8 pa0[2], pa1[2];
        #pragma unroll
        for (int ms = 0; ms < 2; ++ms) {
            half2v xs = __builtin_bit_cast(half2v,
                __builtin_amdgcn_perm(xiu[ms], xiu[ms], 0x01000100u));  // dup fp16 lo->hi
            union { half8 h8; half2v h2[4]; } u0, u1;
            #pragma unroll
            for (int q2 = 0; q2 < 4; ++q2) {
                u0.h2[q2] = xs * xjh[ms][q2];       // v_pk_mul_f16
                u1.h2[q2] = xs * xjh[ms][4 + q2];
            }
            pa0[ms] = u0.h8;
            pa1[ms] = u1.h8;
        }

        // 16 MFMAs, accumulating in C; 8 independent chains keep the pipe full
        #pragma unroll
        for (int ns = 0; ns < 4; ++ns) {
            #pragma unroll
            for (int ms = 0; ms < 2; ++ms) {
                acc[ms][ns] = __builtin_amdgcn_mfma_f32_16x16x32_f16(
                    pa0[ms], bfr[ns][0], acc[ms][ns], 0, 0, 0);
                acc[ms][ns] = __builtin_amdgcn_mfma_f32_16x16x32_f16(
                    pa1[ms], bfr[ns][1], acc[ms][ns], 0, 0, 0);
            }
        }

        // pack W(a+1) (in wreg) into the other buffer; then prefetch W(a+2)
        if (a + 1 < ND) {
            uint16_t* bd = bdst0 + (cur ^ 1) * BT_BUF;
            uint4v q0 = (uint4v){ pk16(wreg[0].x, wreg[0].y), pk16(wreg[0].z, wreg[0].w),
                                  pk16(wreg[1].x, wreg[1].y), pk16(wreg[1].z, wreg[1].w) };
            uint4v q1 = (uint4v){ pk16(wreg[2].x, wreg[2].y), pk16(wreg[2].z, wreg[2].w),
                                  pk16(wreg[3].x, wreg[3].y), pk16(wreg[3].z, wreg[3].w) };
            *(uint4v*)(bd)     = q0;
            *(uint4v*)(bd + 8) = q1;
        }
        if (a + 2 < ND) {
            const float* wn = wsrc + (size_t)(a + 2) * ND;
            #pragma unroll
            for (int q = 0; q < 4; ++q) wreg[q] = *(const floatx4*)(wn + q * 4);
        }

        __syncthreads();  // single barrier per a-step (dbuf makes this safe)
    }

    // ---- epilogue: bias + store. C/D: col = lane&15, row = quad*4 + reg ----
    #pragma unroll
    for (int ns = 0; ns < 4; ++ns) {
        const float bb = bias[p * ND + ns*16 + r];
        #pragma unroll
        for (int ms = 0; ms < 2; ++ms) {
            #pragma unroll
            for (int reg = 0; reg < 4; ++reg) {
                const int row = b0 + wave*32 + ms*16 + quad*4 + reg;
                out[(size_t)row * OUT_STRIDE + p * ND + ns*16 + r]
                    = acc[ms][ns][reg] + bb;
            }
        }
    }
}

extern "C" void kernel_launch(void* const* d_in, const int* in_sizes, int n_in,
                              void* d_out, int out_size, void* d_ws, size_t ws_size,
                              hipStream_t stream) {
    const float* x    = (const float*)d_in[0];  // (1024, 16, 64)
    const float* W    = (const float*)d_in[1];  // (120, 64, 4096)
    const float* bias = (const float*)d_in[2];  // (120, 64)
    float* out = (float*)d_out;                 // (1024, 120, 64)

    dim3 grid(NP, NB / BM);    // 960 blocks; same-p blocks land on one XCD (120 % 8 == 0)
    outer_kernel<<<grid, 256, 0, stream>>>(x, W, bias, out);
}

// Round 4
// 218.985 us; speedup vs baseline: 1.1687x; 1.1687x over previous
//
#include <hip/hip_runtime.h>
#include <stdint.h>
#include <stddef.h>

// Problem constants (B, F, D) = (1024, 16, 64); P = 120
constexpr int NB = 1024;
constexpr int NF = 16;
constexpr int ND = 64;
constexpr int NP = 120;
constexpr int KD = ND * ND;          // 4096 contraction length per pair
constexpr int OUT_STRIDE = NP * ND;  // 7680 floats per batch row

constexpr int BM = 256;              // batch rows per block (keeps W-fetch at the R2 level)
// 512 threads = 8 waves, each owning 32 batch rows -> 4 waves/SIMD at 2 blocks/CU

using floatx4 = __attribute__((ext_vector_type(4))) float;
using half8   = __attribute__((ext_vector_type(8))) _Float16;
using half2v  = __attribute__((ext_vector_type(2))) _Float16;
using fp16x2  = __attribute__((ext_vector_type(2))) __fp16;   // cvt_pkrtz return type
using uint4v  = __attribute__((ext_vector_type(4))) uint32_t;

constexpr int XT_STRIDE = BM;              // u16 per xi^T row (m-contiguous): 256
constexpr int BT_STRIDE = ND;              // u16 per W-tile row: 64, no pad (XOR-swizzled granules)
constexpr int BT_BUF    = ND * BT_STRIDE;  // 4096 u16 = 8 KiB per buffer

// pack 2 f32 -> 2 fp16 (v_cvt_pkrtz_f16_f32, 1 VALU op)
__device__ __forceinline__ half2v pkh2(float f0, float f1) {
    fp16x2 h = __builtin_amdgcn_cvt_pkrtz(f0, f1);
    return __builtin_bit_cast(half2v, h);
}
__device__ __forceinline__ uint32_t pk16(float f0, float f1) {
    fp16x2 h = __builtin_amdgcn_cvt_pkrtz(f0, f1);
    return __builtin_bit_cast(uint32_t, h);
}
__device__ __forceinline__ uint16_t f16bits(float f) {
    return __builtin_bit_cast(uint16_t, (_Float16)f);   // RNE scalar cvt
}

__global__ __launch_bounds__(512, 4)
void outer_kernel(const float* __restrict__ x, const float* __restrict__ W,
                  const float* __restrict__ bias, float* __restrict__ out)
{
    __shared__ uint16_t lds_xit[ND * XT_STRIDE];  // xi^T fp16: 32,768 B
    __shared__ uint16_t lds_bt[2 * BT_BUF];       // W a-tile dbuf: 16,384 B (total 49,152 -> 2 blocks/CU)

    const int p  = blockIdx.x;        // pair 0..119
    const int b0 = blockIdx.y * BM;   // batch tile origin

    // triu_indices(16, k=1) order
    int icol = 0, rem = p;
    while (rem >= NF - 1 - icol) { rem -= NF - 1 - icol; ++icol; }
    const int jcol = icol + 1 + rem;

    const int t    = threadIdx.x;
    const int wave = t >> 6;
    const int lane = t & 63;
    const int r    = lane & 15;
    const int quad = lane >> 4;

    // ---- stage xi transposed: lds_xit[a*XT_STRIDE + m] = fp16(x[b0+m][icol][a]) ----
    // 512 threads cover 256 rows x 64 a: thread handles (row t>>1, a-half (t&1)*32)
    {
        const int mrow  = t >> 1;
        const int chalf = (t & 1) * 32;
        const float* src = x + (size_t)(b0 + mrow) * (NF * ND) + icol * ND + chalf;
        #pragma unroll
        for (int c = 0; c < 32; c += 4) {
            floatx4 v = *(const floatx4*)(src + c);
            lds_xit[(chalf + c + 0) * XT_STRIDE + mrow] = f16bits(v.x);
            lds_xit[(chalf + c + 1) * XT_STRIDE + mrow] = f16bits(v.y);
            lds_xit[(chalf + c + 2) * XT_STRIDE + mrow] = f16bits(v.z);
            lds_xit[(chalf + c + 3) * XT_STRIDE + mrow] = f16bits(v.w);
        }
    }

    // ---- loop-invariant xj as fp16 pairs, laid out to match the MFMA A-fragment ----
    // lane owns A[m = lane&15][k = quad*8 + j]; xjh[ms][ks*4+q] = (c, c+1) at c = ks*32 + quad*8 + 2q
    half2v xjh[2][8];
    #pragma unroll
    for (int ms = 0; ms < 2; ++ms) {
        const float* srow = x + (size_t)(b0 + wave*32 + ms*16 + r) * (NF * ND)
                              + jcol * ND + quad * 8;
        #pragma unroll
        for (int ks = 0; ks < 2; ++ks) {
            floatx4 v0 = *(const floatx4*)(srow + ks * 32);
            floatx4 v1 = *(const floatx4*)(srow + ks * 32 + 4);
            xjh[ms][ks*4 + 0] = pkh2(v0.x, v0.y);
            xjh[ms][ks*4 + 1] = pkh2(v0.z, v0.w);
            xjh[ms][ks*4 + 2] = pkh2(v1.x, v1.y);
            xjh[ms][ks*4 + 3] = pkh2(v1.z, v1.w);
        }
    }

    // ---- W staging: thread covers (n_st, granule cg) of the 64x64 a-tile ----
    // XOR swizzle: source granule cg stored at slot cg ^ (n_st & 7) -> conflict-free write AND read
    const int n_st = t >> 3;
    const int cg   = t & 7;
    const float* wsrc = W + ((size_t)p * ND + n_st) * KD + cg * 8;
    uint16_t* bdst0 = &lds_bt[n_st * BT_STRIDE + ((cg ^ (n_st & 7)) * 8)];

    floatx4 wreg[2];

    // prologue: stage W(0) into buf0; prefetch W(1) into wreg
    wreg[0] = *(const floatx4*)(wsrc);
    wreg[1] = *(const floatx4*)(wsrc + 4);
    {
        uint4v q0 = (uint4v){ pk16(wreg[0].x, wreg[0].y), pk16(wreg[0].z, wreg[0].w),
                              pk16(wreg[1].x, wreg[1].y), pk16(wreg[1].z, wreg[1].w) };
        *(uint4v*)(bdst0) = q0;
    }
    wreg[0] = *(const floatx4*)(wsrc + ND);
    wreg[1] = *(const floatx4*)(wsrc + ND + 4);
    __syncthreads();

    floatx4 acc[2][4] = {};   // fp32 MFMA C-accumulators

    // B-fragment read offsets (u16): first granule quad ^ (r&7); second is ^32 (granule+4)
    const int xg0 = (quad ^ (r & 7)) * 8;

    #pragma unroll 1
    for (int a = 0; a < ND; ++a) {
        const int cur = a & 1;
        const uint16_t* rbuf = lds_bt + cur * BT_BUF;  // holds W(a)

        // xi scalars for this a (broadcast across quads; conflict-free)
        uint32_t xiu[2];
        #pragma unroll
        for (int ms = 0; ms < 2; ++ms)
            xiu[ms] = lds_xit[a * XT_STRIDE + wave*32 + ms*16 + r];

        // B-fragments for all ns (issue LDS reads early; latency covered by A'-build)
        half8 bfr[4][2];
        #pragma unroll
        for (int ns = 0; ns < 4; ++ns) {
            const int rowb = (ns*16 + r) * BT_STRIDE;
            bfr[ns][0] = *(const half8*)&rbuf[rowb + xg0];
            bfr[ns][1] = *(const half8*)&rbuf[rowb + (xg0 ^ 32)];
        }

        // A' = (xi[m,a] * xj[m,c]) fragments — pure producer, no MFMA-result reads
        half8 pa0[2], pa1[2];
        #pragma unroll
        for (int ms = 0; ms < 2; ++ms) {
            half2v xs = __builtin_bit_cast(half2v,
                __builtin_amdgcn_perm(xiu[ms], xiu[ms], 0x01000100u));  // dup fp16 lo->hi
            union { half8 h8; half2v h2[4]; } u0, u1;
            #pragma unroll
            for (int q2 = 0; q2 < 4; ++q2) {
                u0.h2[q2] = xs * xjh[ms][q2];       // v_pk_mul_f16
                u1.h2[q2] = xs * xjh[ms][4 + q2];
            }
            pa0[ms] = u0.h8;
            pa1[ms] = u1.h8;
        }

        // 16 MFMAs, accumulating in C; 8 independent chains keep the pipe full
        #pragma unroll
        for (int ns = 0; ns < 4; ++ns) {
            #pragma unroll
            for (int ms = 0; ms < 2; ++ms) {
                acc[ms][ns] = __builtin_amdgcn_mfma_f32_16x16x32_f16(
                    pa0[ms], bfr[ns][0], acc[ms][ns], 0, 0, 0);
                acc[ms][ns] = __builtin_amdgcn_mfma_f32_16x16x32_f16(
                    pa1[ms], bfr[ns][1], acc[ms][ns], 0, 0, 0);
            }
        }

        // pack W(a+1) (in wreg) into the other buffer; then prefetch W(a+2)
        if (a + 1 < ND) {
            uint16_t* bd = bdst0 + (cur ^ 1) * BT_BUF;
            uint4v q0 = (uint4v){ pk16(wreg[0].x, wreg[0].y), pk16(wreg[0].z, wreg[0].w),
                                  pk16(wreg[1].x, wreg[1].y), pk16(wreg[1].z, wreg[1].w) };
            *(uint4v*)(bd) = q0;
        }
        if (a + 2 < ND) {
            const float* wn = wsrc + (size_t)(a + 2) * ND;
            wreg[0] = *(const floatx4*)(wn);
            wreg[1] = *(const floatx4*)(wn + 4);
        }

        __syncthreads();  // single barrier per a-step (dbuf makes this safe)
    }

    // ---- epilogue: bias + store. C/D: col = lane&15, row = quad*4 + reg ----
    #pragma unroll
    for (int ns = 0; ns < 4; ++ns) {
        const float bb = bias[p * ND + ns*16 + r];
        #pragma unroll
        for (int ms = 0; ms < 2; ++ms) {
            #pragma unroll
            for (int reg = 0; reg < 4; ++reg) {
                const int row = b0 + wave*32 + ms*16 + quad*4 + reg;
                out[(size_t)row * OUT_STRIDE + p * ND + ns*16 + r]
                    = acc[ms][ns][reg] + bb;
            }
        }
    }
}

extern "C" void kernel_launch(void* const* d_in, const int* in_sizes, int n_in,
                              void* d_out, int out_size, void* d_ws, size_t ws_size,
                              hipStream_t stream) {
    const float* x    = (const float*)d_in[0];  // (1024, 16, 64)
    const float* W    = (const float*)d_in[1];  // (120, 64, 4096)
    const float* bias = (const float*)d_in[2];  // (120, 64)
    float* out = (float*)d_out;                 // (1024, 120, 64)

    dim3 grid(NP, NB / BM);    // 480 blocks; same-p blocks land on one XCD (120 % 8 == 0)
    outer_kernel<<<grid, 512, 0, stream>>>(x, W, bias, out);
}